// Round 14
// baseline (519.321 us; speedup 1.0000x reference)
//
#include <hip/hip_runtime.h>
#include <hip/hip_bf16.h>
#include <cstdio>
#include <cstdint>

typedef __bf16 bf16_t;
typedef __bf16 bf16x8 __attribute__((ext_vector_type(8)));
typedef float f32x4 __attribute__((ext_vector_type(4)));

static constexpr int Bc = 2, Sc = 1024, HIDc = 4096;
static constexpr int NQc = 32, NKVc = 8, Dc = 128, OFFc = 1024, Tc = 2048;
static constexpr int Mrows = Bc * Sc;                 // 2048
static constexpr int NQKV = (NQc + 2 * NKVc) * Dc;    // 6144

__device__ inline void load_lds16(const void* g, void* l) {
    __builtin_amdgcn_global_load_lds(
        (const __attribute__((address_space(1))) unsigned*)g,
        (__attribute__((address_space(3))) unsigned*)l, 16, 0, 0);
}

// ---------------- fp32 -> bf16 convert ----------------
__global__ void k_cvt(const float* __restrict__ src, bf16_t* __restrict__ dst, long n4) {
    long i = blockIdx.x * (long)blockDim.x + threadIdx.x;
    long stride = (long)gridDim.x * blockDim.x;
    const float4* s4 = (const float4*)src;
    for (; i < n4; i += stride) {
        float4 v = s4[i];
        bf16_t t[4] = {(bf16_t)v.x, (bf16_t)v.y, (bf16_t)v.z, (bf16_t)v.w};
        *(uint2*)&dst[i * 4] = *(uint2*)t;
    }
}

// ---------------- GEMM (R10-proven m97 structure + bank-spread swizzle) -----
// C[M][N] = A[M][K] * B[N][K]^T (+bias). 128x128 tile, BK=32, 4 waves,
// global_load_lds w16, bijective XCD swizzle. LDS rows are 4x16B units;
// staged as LDS[row][u] = G[row][u ^ (row&3)] (linear dest, pre-swizzled
// source); reads use the same involution -> each 32-lane half spreads over
// all 32 banks (was: half the banks -> 1.26e7 conflict cycles in R10).
template <bool BIAS, bool OUT_BF16>
__global__ __launch_bounds__(256) void k_gemm(const bf16_t* __restrict__ A,
                                              const bf16_t* __restrict__ Bm,
                                              const float* __restrict__ bias,
                                              void* __restrict__ Cout,
                                              int M, int N, int K) {
    __shared__ __align__(16) bf16_t As[128][32];
    __shared__ __align__(16) bf16_t Bs[128][32];
    const int tid = threadIdx.x, wid = tid >> 6, lane = tid & 63;
    const int g = lane >> 4, ln = lane & 15;
    const int wm = wid >> 1, wn = wid & 1;
    const int gx = gridDim.x;
    int bidl = blockIdx.y * gx + blockIdx.x;
    int cpx = (gx * gridDim.y) >> 3;
    int swz = (bidl & 7) * cpx + (bidl >> 3);
    const int m0 = (swz / gx) * 128, n0 = (swz % gx) * 128;
    f32x4 acc[4][4] = {};

    for (int k0 = 0; k0 < K; k0 += 32) {
        __syncthreads();
#pragma unroll
        for (int c = 0; c < 2; ++c) {
            int row = wid * 32 + c * 16 + (lane >> 2);
            int col = (((lane & 3) ^ (row & 3)) * 8);   // pre-swizzled source unit
            load_lds16(A + (size_t)(m0 + row) * K + k0 + col, &As[wid * 32 + c * 16][0]);
            load_lds16(Bm + (size_t)(n0 + row) * K + k0 + col, &Bs[wid * 32 + c * 16][0]);
        }
        __syncthreads();
        bf16x8 af[4], bfr[4];
#pragma unroll
        for (int i = 0; i < 4; ++i) {
            int row = wm * 64 + i * 16 + ln;
            af[i] = *(const bf16x8*)&As[row][(g ^ (row & 3)) * 8];
        }
#pragma unroll
        for (int i = 0; i < 4; ++i) {
            int row = wn * 64 + i * 16 + ln;
            bfr[i] = *(const bf16x8*)&Bs[row][(g ^ (row & 3)) * 8];
        }
#pragma unroll
        for (int i = 0; i < 4; ++i)
#pragma unroll
            for (int j = 0; j < 4; ++j)
                acc[i][j] = __builtin_amdgcn_mfma_f32_16x16x32_bf16(af[i], bfr[j], acc[i][j], 0, 0, 0);
    }

#pragma unroll
    for (int i = 0; i < 4; ++i) {
#pragma unroll
        for (int j = 0; j < 4; ++j) {
            int col = n0 + wn * 64 + j * 16 + ln;
            float bv = BIAS ? bias[col] : 0.f;
#pragma unroll
            for (int r = 0; r < 4; ++r) {
                int row = m0 + wm * 64 + i * 16 + g * 4 + r;
                float v = acc[i][j][r] + bv;
                if (OUT_BF16)
                    ((bf16_t*)Cout)[(size_t)row * N + col] = (bf16_t)v;
                else
                    ((float*)Cout)[(size_t)row * N + col] = v;
            }
        }
    }
}

// ---------------- RoPE q in place ----------------
__global__ void k_rope_q(bf16_t* __restrict__ qkv, const float* __restrict__ cosT,
                         const float* __restrict__ sinT) {
    int row = blockIdx.x;            // 0..2047 = b*1024 + s
    int s = row & 1023;
    bf16_t* src = qkv + (size_t)row * NQKV;
    for (int p = threadIdx.x; p < 2048; p += 256) {
        int j = p & 63;
        float c = cosT[s * 64 + j], sn = sinT[s * 64 + j];
        float xr = (float)src[2 * p], xi = (float)src[2 * p + 1];
        src[2 * p]     = (bf16_t)(xr * c - xi * sn);
        src[2 * p + 1] = (bf16_t)(xr * sn + xi * c);
    }
}

// Frag layouts PER Q-HEAD (b,h), flat size Tc*Dc each. Each 64-token tile t
// occupies the CONTIGUOUS elem range [t*8192, (t+1)*8192):
//  kfr: idx(t,d) = ((t16*4+dc)*4+g)*128 + ln*8 + e   [t16=t>>4, ln=t&15; dc=d>>5, g=(d>>3)&3, e=d&7]
//  vfr: idx(t,d) = (((tile*8+d16)*2+kc)*4+gk)*128 + ln*8 + e
//       [tile=t>>6, kc=(t>>5)&1, gk=(t>>3)&3, e=t&7; d16=d>>4, ln=d&15]

// ---------------- RoPE k + scatter new K/V ----------------
// grid (sb=16, hk=8, b=2), 256 threads
__global__ __launch_bounds__(256) void k_ropekv(const bf16_t* __restrict__ qkv,
                                                const float* __restrict__ cosT,
                                                const float* __restrict__ sinT,
                                                float* __restrict__ out_k,
                                                float* __restrict__ out_v,
                                                bf16_t* __restrict__ kfr,
                                                bf16_t* __restrict__ vfr) {
    __shared__ __align__(16) bf16_t Vl[64][136];
    const int sb = blockIdx.x, hk = blockIdx.y, b = blockIdx.z;
    const int tid = threadIdx.x;
    const int tt = tid >> 2, dq = (tid & 3) * 32;
    const int s = sb * 64 + tt;
    const int t = OFFc + s;
    const bf16_t* krow = qkv + (size_t)(b * Sc + s) * NQKV + NQc * Dc + hk * Dc + dq;
    const bf16_t* vrow = qkv + (size_t)(b * Sc + s) * NQKV + (NQc + NKVc) * Dc + hk * Dc + dq;

    float cs[16], sn[16];
    int j0 = dq >> 1;
#pragma unroll
    for (int q4 = 0; q4 < 4; ++q4) {
        float4 cv = *(const float4*)&cosT[s * 64 + j0 + q4 * 4];
        float4 sv = *(const float4*)&sinT[s * 64 + j0 + q4 * 4];
        cs[q4 * 4] = cv.x; cs[q4 * 4 + 1] = cv.y; cs[q4 * 4 + 2] = cv.z; cs[q4 * 4 + 3] = cv.w;
        sn[q4 * 4] = sv.x; sn[q4 * 4 + 1] = sv.y; sn[q4 * 4 + 2] = sv.z; sn[q4 * 4 + 3] = sv.w;
    }

    bf16_t kb[32], vb[32];
#pragma unroll
    for (int c = 0; c < 4; ++c) {
        *(uint4*)&kb[c * 8] = *(const uint4*)&krow[c * 8];
        *(uint4*)&vb[c * 8] = *(const uint4*)&vrow[c * 8];
    }
    float ko[32], vo[32];
    bf16_t kbf[32];
#pragma unroll
    for (int jj = 0; jj < 16; ++jj) {
        float xr = (float)kb[2 * jj], xi = (float)kb[2 * jj + 1];
        ko[2 * jj]     = xr * cs[jj] - xi * sn[jj];
        ko[2 * jj + 1] = xr * sn[jj] + xi * cs[jj];
        kbf[2 * jj]     = (bf16_t)ko[2 * jj];
        kbf[2 * jj + 1] = (bf16_t)ko[2 * jj + 1];
        vo[2 * jj] = (float)vb[2 * jj];
        vo[2 * jj + 1] = (float)vb[2 * jj + 1];
    }

    const int t16 = t >> 4, lnr = t & 15, dc = dq >> 5;
#pragma unroll
    for (int gg = 0; gg < 4; ++gg) {
        int hq = hk * 4 + gg;
        size_t o = ((size_t)(b * Tc + t) * NQc + hq) * Dc + dq;
#pragma unroll
        for (int c = 0; c < 8; ++c) {
            *(float4*)&out_k[o + c * 4] = *(float4*)&ko[c * 4];
            *(float4*)&out_v[o + c * 4] = *(float4*)&vo[c * 4];
        }
        size_t fb = ((size_t)b * NQc + hq) * ((size_t)Tc * Dc);
#pragma unroll
        for (int g = 0; g < 4; ++g)
            *(uint4*)&kfr[fb + (size_t)(((t16 * 4 + dc) * 4 + g) * 128 + lnr * 8)] = *(uint4*)&kbf[g * 8];
    }
    // LDS transpose of v -> vfr subtiles (replicated over the 4 q-heads)
#pragma unroll
    for (int c = 0; c < 4; ++c) *(uint4*)&Vl[tt][dq + c * 8] = *(uint4*)&vb[c * 8];
    __syncthreads();
    const int tile = 16 + sb;
#pragma unroll
    for (int i = 0; i < 4; ++i) {
        int u = i * 256 + tid;
        int d = u >> 3, cc = u & 7;
        bf16_t tmp[8];
#pragma unroll
        for (int j = 0; j < 8; ++j) tmp[j] = Vl[cc * 8 + j][d];
        size_t off = (size_t)((((tile * 8 + (d >> 4)) * 2 + (cc >> 2)) * 4 + (cc & 3)) * 128 + (d & 15) * 8);
#pragma unroll
        for (int gg = 0; gg < 4; ++gg) {
            int hq = hk * 4 + gg;
            size_t fb = ((size_t)b * NQc + hq) * ((size_t)Tc * Dc);
            *(uint4*)&vfr[fb + off] = *(uint4*)tmp;
        }
    }
}

// ---------------- cache copy + frag layouts (ALL 32 heads independent) ------
// grid (tb=16, h=32, b=2), 256 threads
__global__ __launch_bounds__(256) void k_cache(const float* __restrict__ kc,
                                               const float* __restrict__ vc,
                                               float* __restrict__ out_k,
                                               float* __restrict__ out_v,
                                               bf16_t* __restrict__ kfr,
                                               bf16_t* __restrict__ vfr) {
    __shared__ __align__(16) bf16_t Vl[64][136];
    const int tb = blockIdx.x, h = blockIdx.y, b = blockIdx.z;
    const int tid = threadIdx.x;
    const int tt = tid >> 2, dq = (tid & 3) * 32;
    const int t = tb * 64 + tt;
    size_t src = ((size_t)(b * OFFc + t) * NQc + h) * Dc + dq;
    size_t dst = ((size_t)(b * Tc + t) * NQc + h) * Dc + dq;
    const size_t fb = ((size_t)b * NQc + h) * ((size_t)Tc * Dc);

    bf16_t kb[32], vb[32];
#pragma unroll
    for (int c = 0; c < 8; ++c) {
        float4 kv = *(const float4*)&kc[src + c * 4];
        *(float4*)&out_k[dst + c * 4] = kv;
        kb[c * 4] = (bf16_t)kv.x; kb[c * 4 + 1] = (bf16_t)kv.y;
        kb[c * 4 + 2] = (bf16_t)kv.z; kb[c * 4 + 3] = (bf16_t)kv.w;
        float4 vv = *(const float4*)&vc[src + c * 4];
        *(float4*)&out_v[dst + c * 4] = vv;
        vb[c * 4] = (bf16_t)vv.x; vb[c * 4 + 1] = (bf16_t)vv.y;
        vb[c * 4 + 2] = (bf16_t)vv.z; vb[c * 4 + 3] = (bf16_t)vv.w;
    }
    const int t16 = t >> 4, lnr = t & 15, dc = dq >> 5;
#pragma unroll
    for (int g = 0; g < 4; ++g)
        *(uint4*)&kfr[fb + (size_t)(((t16 * 4 + dc) * 4 + g) * 128 + lnr * 8)] = *(uint4*)&kb[g * 8];

#pragma unroll
    for (int c = 0; c < 4; ++c) *(uint4*)&Vl[tt][dq + c * 8] = *(uint4*)&vb[c * 8];
    __syncthreads();
#pragma unroll
    for (int i = 0; i < 4; ++i) {
        int u = i * 256 + tid;
        int d = u >> 3, cc = u & 7;
        bf16_t tmp[8];
#pragma unroll
        for (int j = 0; j < 8; ++j) tmp[j] = Vl[cc * 8 + j][d];
        size_t off = (size_t)((((tb * 8 + (d >> 4)) * 2 + (cc >> 2)) * 4 + (cc & 3)) * 128 + (d & 15) * 8);
        *(uint4*)&vfr[fb + off] = *(uint4*)tmp;
    }
}

// ---------------- flash attention v5: 8 waves + swapped QK^T ----------------
// 256 blocks x 512 threads (8 waves x 32 q-rows = 256 q-rows/block).
// K/V LDS-staged double-buffered (64KB, R8-proven); swapped mfma(K,Q) gives a
// full P-row per lane: in-lane max/sum + 2 shfl, P stored as 8 b64 writes per
// tile into pad-72 rows (no swizzle needed), PV A-frags read as b128.
__global__ __launch_bounds__(512) void k_attn(const bf16_t* __restrict__ qkv,
                                              const bf16_t* __restrict__ kfr,
                                              const bf16_t* __restrict__ vfr,
                                              bf16_t* __restrict__ attn) {
    __shared__ __align__(16) bf16_t Kl[2][8192];   // 32 KB
    __shared__ __align__(16) bf16_t Vl2[2][8192];  // 32 KB
    __shared__ __align__(16) bf16_t Pl[8][32 * 72];// 36 KB (pad-72 rows)
    const int tid = threadIdx.x, w = tid >> 6, l = tid & 63;
    const int g = l >> 4, ln = l & 15;
    const int bid = blockIdx.x;
    const int xcd = bid & 7, within = bid >> 3;    // 0..31
    const int qblk = 3 - (within & 3);             // longest q-blocks first
    const int u = within >> 2;                     // 0..7
    const int b = u >> 2;
    const int h = (u & 3) * 8 + xcd;
    const int q0b = qblk * 256;
    const int qw0 = q0b + w * 32;
    const float SCALE = 0.08838834764831845f;
    const float L2E = 1.4426950408889634f;
    const size_t hb = ((size_t)b * NQc + h) * ((size_t)Tc * Dc);
    const bf16_t* kb = kfr + hb;
    const bf16_t* vb = vfr + hb;
    bf16_t* Pw = &Pl[w][0];

    bf16x8 qf[2][4];
#pragma unroll
    for (int mf = 0; mf < 2; ++mf) {
        size_t qrow = (size_t)(b * Sc + qw0 + mf * 16 + ln) * NQKV + h * Dc;
#pragma unroll
        for (int dc = 0; dc < 4; ++dc) qf[mf][dc] = *(const bf16x8*)&qkv[qrow + dc * 32 + g * 8];
    }
    f32x4 o[2][8] = {};
    float mrun[2] = {-1e30f, -1e30f};   // per lane: row q = mf*16 + ln
    float lrun[2] = {0.f, 0.f};

    const int ntiles = (OFFc + q0b + 256) >> 6;    // block covers tokens < OFF+q0b+256

    // stage tile t into buffer bf: each wave copies its 2 chunks of K and V
    auto stage = [&](int bf, int t) {
        const bf16_t* ksrc = kb + (size_t)t * 8192 + (size_t)(w * 2) * 512;
        const bf16_t* vsrc = vb + (size_t)t * 8192 + (size_t)(w * 2) * 512;
        load_lds16(ksrc + (size_t)l * 8,       &Kl[bf][(w * 2) * 512]);
        load_lds16(ksrc + 512 + (size_t)l * 8, &Kl[bf][(w * 2 + 1) * 512]);
        load_lds16(vsrc + (size_t)l * 8,       &Vl2[bf][(w * 2) * 512]);
        load_lds16(vsrc + 512 + (size_t)l * 8, &Vl2[bf][(w * 2 + 1) * 512]);
    };

    stage(0, 0);
    __syncthreads();
    int cur = 0;

    for (int t = 0; t < ntiles; ++t) {
        if (t + 1 < ntiles) stage(cur ^ 1, t + 1);
        // ---- QK^T (swapped): lane (g,ln) holds S[t=nf*16+g*4+r][q=mf*16+ln] ----
        f32x4 sa[2][4] = {};
#pragma unroll
        for (int nf = 0; nf < 4; ++nf) {
            bf16x8 kf[4];
#pragma unroll
            for (int dc = 0; dc < 4; ++dc)
                kf[dc] = *(const bf16x8*)&Kl[cur][((nf * 4 + dc) * 4 + g) * 128 + ln * 8];
#pragma unroll
            for (int dc = 0; dc < 4; ++dc) {
                sa[0][nf] = __builtin_amdgcn_mfma_f32_16x16x32_bf16(kf[dc], qf[0][dc], sa[0][nf], 0, 0, 0);
                sa[1][nf] = __builtin_amdgcn_mfma_f32_16x16x32_bf16(kf[dc], qf[1][dc], sa[1][nf], 0, 0, 0);
            }
        }
        // ---- scale + causal mask ----
        bool maybe = (t * 64 + 63 > OFFc + qw0);
#pragma unroll
        for (int mf = 0; mf < 2; ++mf)
#pragma unroll
            for (int nf = 0; nf < 4; ++nf)
#pragma unroll
                for (int r = 0; r < 4; ++r) {
                    float s = sa[mf][nf][r] * SCALE;
                    if (maybe) {
                        int tg = t * 64 + nf * 16 + g * 4 + r;
                        int qg = qw0 + mf * 16 + ln;
                        if (tg > OFFc + qg) s = -1e30f;
                    }
                    sa[mf][nf][r] = s;
                }
        // ---- row max (15 in-lane + 2 shfl) + exact skip-rescale ----
        float tm[2];
        int grew = 0;
#pragma unroll
        for (int mf = 0; mf < 2; ++mf) {
            float m2 = sa[mf][0][0];
#pragma unroll
            for (int nf = 0; nf < 4; ++nf)
#pragma unroll
                for (int r = 0; r < 4; ++r) m2 = fmaxf(m2, sa[mf][nf][r]);
            m2 = fmaxf(m2, __shfl_xor(m2, 16));
            m2 = fmaxf(m2, __shfl_xor(m2, 32));
            tm[mf] = m2;
            grew |= (m2 > mrun[mf]) ? 1 : 0;
        }
        if (__any(grew)) {
#pragma unroll
            for (int mf = 0; mf < 2; ++mf) {
                float mn = fmaxf(mrun[mf], tm[mf]);
                float al = exp2f((mrun[mf] - mn) * L2E);
                mrun[mf] = mn;
                lrun[mf] *= al;
                // redistribute al (per q=mf*16+ln) to PV row layout q=mf*16+g*4+r
                float alr[4];
#pragma unroll
                for (int r = 0; r < 4; ++r)
                    alr[r] = __shfl(al, (l & 48) | (g * 4 + r));
#pragma unroll
                for (int df = 0; df < 8; ++df) {
                    f32x4 t4 = o[mf][df];
                    t4[0] *= alr[0]; t4[1] *= alr[1]; t4[2] *= alr[2]; t4[3] *= alr[3];
                    o[mf][df] = t4;
                }
            }
        }
        // ---- P = exp (in-lane), l-sum, linear b64 P-store (pad-72 rows) ----
#pragma unroll
        for (int mf = 0; mf < 2; ++mf) {
            const int qrow = mf * 16 + ln;
            float ps = 0.f;
#pragma unroll
            for (int nf = 0; nf < 4; ++nf) {
                bf16_t pv[4];
#pragma unroll
                for (int r = 0; r < 4; ++r) {
                    float p = exp2f((sa[mf][nf][r] - mrun[mf]) * L2E);
                    ps += p;
                    pv[r] = (bf16_t)p;
                }
                *(uint2*)&Pw[qrow * 72 + nf * 16 + g * 4] = *(uint2*)pv;
            }
            ps += __shfl_xor(ps, 16);
            ps += __shfl_xor(ps, 32);
            lrun[mf] += ps;
        }
        // ---- PV from LDS V tile: kc halves sequentially ----
#pragma unroll
        for (int kc = 0; kc < 2; ++kc) {
            bf16x8 vf[8];
#pragma unroll
            for (int df = 0; df < 8; ++df)
                vf[df] = *(const bf16x8*)&Vl2[cur][((df * 2 + kc) * 4 + g) * 128 + ln * 8];
#pragma unroll
            for (int mf = 0; mf < 2; ++mf) {
                bf16x8 pa = *(const bf16x8*)&Pw[(mf * 16 + ln) * 72 + kc * 32 + g * 8];
#pragma unroll
                for (int df = 0; df < 8; ++df)
                    o[mf][df] = __builtin_amdgcn_mfma_f32_16x16x32_bf16(pa, vf[df], o[mf][df], 0, 0, 0);
            }
        }
        __syncthreads();   // drains staged loads for t+1; guards buffer reuse
        cur ^= 1;
    }

    // epilogue: o rows are q = qw0 + mf*16 + g*4 + r; 1/l fetched via shfl
#pragma unroll
    for (int mf = 0; mf < 2; ++mf) {
        float linv[4];
#pragma unroll
        for (int r = 0; r < 4; ++r)
            linv[r] = 1.f / __shfl(lrun[mf], (l & 48) | (g * 4 + r));
#pragma unroll
        for (int df = 0; df < 8; ++df)
#pragma unroll
            for (int r = 0; r < 4; ++r) {
                float v = o[mf][df][r] * linv[r];
                size_t orow = (size_t)(b * Sc + qw0 + mf * 16 + g * 4 + r) * (NQc * Dc) + h * Dc + df * 16 + ln;
                attn[orow] = (bf16_t)v;
            }
    }
}

extern "C" void kernel_launch(void* const* d_in, const int* in_sizes, int n_in,
                              void* d_out, int out_size, void* d_ws, size_t ws_size,
                              hipStream_t stream) {
    const float* x      = (const float*)d_in[0];
    const float* cosT   = (const float*)d_in[2];
    const float* sinT   = (const float*)d_in[3];
    const float* kcache = (const float*)d_in[4];
    const float* vcache = (const float*)d_in[5];
    const float* q_w    = (const float*)d_in[6];
    const float* q_b    = (const float*)d_in[7];
    const float* k_w    = (const float*)d_in[8];
    const float* k_b    = (const float*)d_in[9];
    const float* v_w    = (const float*)d_in[10];
    const float* v_b    = (const float*)d_in[11];
    const float* o_w    = (const float*)d_in[12];

    char* ws = (char*)d_ws;
    size_t off = 0;
    auto alloc = [&](size_t bytes) {
        void* p = ws + off;
        off += (bytes + 255) & ~(size_t)255;
        return p;
    };
    bf16_t* xb   = (bf16_t*)alloc((size_t)Mrows * HIDc * 2);        // reused as attn out
    bf16_t* wqkv = (bf16_t*)alloc((size_t)Bc * Tc * NQc * Dc * 4);  // reused as kfr+vfr
    bf16_t* owb  = (bf16_t*)alloc((size_t)HIDc * HIDc * 2);
    bf16_t* qkv  = (bf16_t*)alloc((size_t)Mrows * NQKV * 2);
    float*  bias = (float*)alloc((size_t)NQKV * 4);
    if (off > ws_size) {
        fprintf(stderr, "WS too small: need %zu have %zu\n", off, ws_size);
        return;
    }
    bf16_t* attn  = xb;
    bf16_t* kfr = wqkv;                                   // 33.55 MB per-head frags
    bf16_t* vfr = wqkv + (size_t)Bc * NQc * Tc * Dc;      // 33.55 MB

    float* out_o = (float*)d_out;
    float* out_k = out_o + (size_t)Mrows * HIDc;
    float* out_v = out_k + (size_t)Bc * Tc * NQc * Dc;

    k_cvt<<<2048, 256, 0, stream>>>(x, xb, (long)Mrows * HIDc / 4);
    k_cvt<<<2048, 256, 0, stream>>>(q_w, wqkv, (long)NQc * Dc * HIDc / 4);
    k_cvt<<<1024, 256, 0, stream>>>(k_w, wqkv + (size_t)NQc * Dc * HIDc, (long)NKVc * Dc * HIDc / 4);
    k_cvt<<<1024, 256, 0, stream>>>(v_w, wqkv + (size_t)(NQc + NKVc) * Dc * HIDc, (long)NKVc * Dc * HIDc / 4);
    k_cvt<<<2048, 256, 0, stream>>>(o_w, owb, (long)HIDc * HIDc / 4);
    (void)hipMemcpyAsync(bias, q_b, (size_t)NQc * Dc * 4, hipMemcpyDeviceToDevice, stream);
    (void)hipMemcpyAsync(bias + NQc * Dc, k_b, (size_t)NKVc * Dc * 4, hipMemcpyDeviceToDevice, stream);
    (void)hipMemcpyAsync(bias + (NQc + NKVc) * Dc, v_b, (size_t)NKVc * Dc * 4, hipMemcpyDeviceToDevice, stream);

    k_gemm<true, true><<<dim3(NQKV / 128, Mrows / 128), 256, 0, stream>>>(
        xb, wqkv, bias, qkv, Mrows, NQKV, HIDc);
    // weights in wqkv are dead after this GEMM; kfr/vfr alias the region and
    // are written only by stream-ordered later kernels.
    k_rope_q<<<Mrows, 256, 0, stream>>>(qkv, cosT, sinT);
    k_ropekv<<<dim3(16, 8, 2), 256, 0, stream>>>(qkv, cosT, sinT, out_k, out_v, kfr, vfr);
    k_cache<<<dim3(16, 32, 2), 256, 0, stream>>>(kcache, vcache, out_k, out_v, kfr, vfr);
    k_attn<<<256, 512, 0, stream>>>(qkv, kfr, vfr, attn);
    k_gemm<false, false><<<dim3(HIDc / 128, Mrows / 128), 256, 0, stream>>>(
        attn, owb, nullptr, d_out, Mrows, HIDc, HIDc);
}

// Round 15
// 501.325 us; speedup vs baseline: 1.0359x; 1.0359x over previous
//
#include <hip/hip_runtime.h>
#include <hip/hip_bf16.h>
#include <cstdio>
#include <cstdint>

typedef __bf16 bf16_t;
typedef __bf16 bf16x8 __attribute__((ext_vector_type(8)));
typedef float f32x4 __attribute__((ext_vector_type(4)));

static constexpr int Bc = 2, Sc = 1024, HIDc = 4096;
static constexpr int NQc = 32, NKVc = 8, Dc = 128, OFFc = 1024, Tc = 2048;
static constexpr int Mrows = Bc * Sc;                 // 2048
static constexpr int NQKV = (NQc + 2 * NKVc) * Dc;    // 6144

__device__ inline void load_lds16(const void* g, void* l) {
    __builtin_amdgcn_global_load_lds(
        (const __attribute__((address_space(1))) unsigned*)g,
        (__attribute__((address_space(3))) unsigned*)l, 16, 0, 0);
}

// ---------------- fp32 -> bf16 convert ----------------
__global__ void k_cvt(const float* __restrict__ src, bf16_t* __restrict__ dst, long n4) {
    long i = blockIdx.x * (long)blockDim.x + threadIdx.x;
    long stride = (long)gridDim.x * blockDim.x;
    const float4* s4 = (const float4*)src;
    for (; i < n4; i += stride) {
        float4 v = s4[i];
        bf16_t t[4] = {(bf16_t)v.x, (bf16_t)v.y, (bf16_t)v.z, (bf16_t)v.w};
        *(uint2*)&dst[i * 4] = *(uint2*)t;
    }
}

// ---------------- GEMM (m97 structure, BK=64, bank-spread swizzle) ----------
// C[M][N] = A[M][K] * B[N][K]^T (+bias). 128x128 tile, BK=64, 4 waves,
// global_load_lds w16, bijective XCD swizzle. Rows are 8x16B units (128B =
// exactly 32 banks), so frag reads REQUIRE the involution swizzle:
// LDS[row][u] = G[row][u ^ (row&7)] (linear dest, pre-swizzled source);
// reads use the same XOR -> 8 units x 4 banks x 2 lanes = conflict-free.
// BK=64 halves the vmcnt/lgkmcnt drain + barrier frequency vs BK=32.
template <bool BIAS, bool OUT_BF16>
__global__ __launch_bounds__(256) void k_gemm(const bf16_t* __restrict__ A,
                                              const bf16_t* __restrict__ Bm,
                                              const float* __restrict__ bias,
                                              void* __restrict__ Cout,
                                              int M, int N, int K) {
    __shared__ __align__(16) bf16_t As[128][64];
    __shared__ __align__(16) bf16_t Bs[128][64];
    const int tid = threadIdx.x, wid = tid >> 6, lane = tid & 63;
    const int g = lane >> 4, ln = lane & 15;
    const int wm = wid >> 1, wn = wid & 1;
    const int gx = gridDim.x;
    int bidl = blockIdx.y * gx + blockIdx.x;
    int cpx = (gx * gridDim.y) >> 3;
    int swz = (bidl & 7) * cpx + (bidl >> 3);
    const int m0 = (swz / gx) * 128, n0 = (swz % gx) * 128;
    f32x4 acc[4][4] = {};

    for (int k0 = 0; k0 < K; k0 += 64) {
        __syncthreads();
        // stage: per wave 4+4 loads; each load covers 8 rows (64 lanes x 16B)
#pragma unroll
        for (int c = 0; c < 4; ++c) {
            int row = wid * 32 + c * 8 + (lane >> 3);
            int col = ((lane & 7) ^ (row & 7)) * 8;    // pre-swizzled source unit
            load_lds16(A + (size_t)(m0 + row) * K + k0 + col, &As[wid * 32 + c * 8][0]);
            load_lds16(Bm + (size_t)(n0 + row) * K + k0 + col, &Bs[wid * 32 + c * 8][0]);
        }
        __syncthreads();
#pragma unroll
        for (int kk = 0; kk < 2; ++kk) {
            bf16x8 af[4], bfr[4];
#pragma unroll
            for (int i = 0; i < 4; ++i) {
                int row = wm * 64 + i * 16 + ln;
                af[i] = *(const bf16x8*)&As[row][(((kk * 4 + g) ^ (row & 7)) * 8)];
            }
#pragma unroll
            for (int j = 0; j < 4; ++j) {
                int row = wn * 64 + j * 16 + ln;
                bfr[j] = *(const bf16x8*)&Bs[row][(((kk * 4 + g) ^ (row & 7)) * 8)];
            }
#pragma unroll
            for (int i = 0; i < 4; ++i)
#pragma unroll
                for (int j = 0; j < 4; ++j)
                    acc[i][j] = __builtin_amdgcn_mfma_f32_16x16x32_bf16(af[i], bfr[j], acc[i][j], 0, 0, 0);
        }
    }

#pragma unroll
    for (int i = 0; i < 4; ++i) {
#pragma unroll
        for (int j = 0; j < 4; ++j) {
            int col = n0 + wn * 64 + j * 16 + ln;
            float bv = BIAS ? bias[col] : 0.f;
#pragma unroll
            for (int r = 0; r < 4; ++r) {
                int row = m0 + wm * 64 + i * 16 + g * 4 + r;
                float v = acc[i][j][r] + bv;
                if (OUT_BF16)
                    ((bf16_t*)Cout)[(size_t)row * N + col] = (bf16_t)v;
                else
                    ((float*)Cout)[(size_t)row * N + col] = v;
            }
        }
    }
}

// ---------------- RoPE q in place ----------------
__global__ void k_rope_q(bf16_t* __restrict__ qkv, const float* __restrict__ cosT,
                         const float* __restrict__ sinT) {
    int row = blockIdx.x;            // 0..2047 = b*1024 + s
    int s = row & 1023;
    bf16_t* src = qkv + (size_t)row * NQKV;
    for (int p = threadIdx.x; p < 2048; p += 256) {
        int j = p & 63;
        float c = cosT[s * 64 + j], sn = sinT[s * 64 + j];
        float xr = (float)src[2 * p], xi = (float)src[2 * p + 1];
        src[2 * p]     = (bf16_t)(xr * c - xi * sn);
        src[2 * p + 1] = (bf16_t)(xr * sn + xi * c);
    }
}

// Frag layouts PER Q-HEAD (b,h), flat size Tc*Dc each. Each 64-token tile t
// occupies the CONTIGUOUS elem range [t*8192, (t+1)*8192):
//  kfr: idx(t,d) = ((t16*4+dc)*4+g)*128 + ln*8 + e   [t16=t>>4, ln=t&15; dc=d>>5, g=(d>>3)&3, e=d&7]
//  vfr: idx(t,d) = (((tile*8+d16)*2+kc)*4+gk)*128 + ln*8 + e
//       [tile=t>>6, kc=(t>>5)&1, gk=(t>>3)&3, e=t&7; d16=d>>4, ln=d&15]

// ---------------- RoPE k + scatter new K/V ----------------
// grid (sb=16, hk=8, b=2), 256 threads
__global__ __launch_bounds__(256) void k_ropekv(const bf16_t* __restrict__ qkv,
                                                const float* __restrict__ cosT,
                                                const float* __restrict__ sinT,
                                                float* __restrict__ out_k,
                                                float* __restrict__ out_v,
                                                bf16_t* __restrict__ kfr,
                                                bf16_t* __restrict__ vfr) {
    __shared__ __align__(16) bf16_t Vl[64][136];
    const int sb = blockIdx.x, hk = blockIdx.y, b = blockIdx.z;
    const int tid = threadIdx.x;
    const int tt = tid >> 2, dq = (tid & 3) * 32;
    const int s = sb * 64 + tt;
    const int t = OFFc + s;
    const bf16_t* krow = qkv + (size_t)(b * Sc + s) * NQKV + NQc * Dc + hk * Dc + dq;
    const bf16_t* vrow = qkv + (size_t)(b * Sc + s) * NQKV + (NQc + NKVc) * Dc + hk * Dc + dq;

    float cs[16], sn[16];
    int j0 = dq >> 1;
#pragma unroll
    for (int q4 = 0; q4 < 4; ++q4) {
        float4 cv = *(const float4*)&cosT[s * 64 + j0 + q4 * 4];
        float4 sv = *(const float4*)&sinT[s * 64 + j0 + q4 * 4];
        cs[q4 * 4] = cv.x; cs[q4 * 4 + 1] = cv.y; cs[q4 * 4 + 2] = cv.z; cs[q4 * 4 + 3] = cv.w;
        sn[q4 * 4] = sv.x; sn[q4 * 4 + 1] = sv.y; sn[q4 * 4 + 2] = sv.z; sn[q4 * 4 + 3] = sv.w;
    }

    bf16_t kb[32], vb[32];
#pragma unroll
    for (int c = 0; c < 4; ++c) {
        *(uint4*)&kb[c * 8] = *(const uint4*)&krow[c * 8];
        *(uint4*)&vb[c * 8] = *(const uint4*)&vrow[c * 8];
    }
    float ko[32], vo[32];
    bf16_t kbf[32];
#pragma unroll
    for (int jj = 0; jj < 16; ++jj) {
        float xr = (float)kb[2 * jj], xi = (float)kb[2 * jj + 1];
        ko[2 * jj]     = xr * cs[jj] - xi * sn[jj];
        ko[2 * jj + 1] = xr * sn[jj] + xi * cs[jj];
        kbf[2 * jj]     = (bf16_t)ko[2 * jj];
        kbf[2 * jj + 1] = (bf16_t)ko[2 * jj + 1];
        vo[2 * jj] = (float)vb[2 * jj];
        vo[2 * jj + 1] = (float)vb[2 * jj + 1];
    }

    const int t16 = t >> 4, lnr = t & 15, dc = dq >> 5;
#pragma unroll
    for (int gg = 0; gg < 4; ++gg) {
        int hq = hk * 4 + gg;
        size_t o = ((size_t)(b * Tc + t) * NQc + hq) * Dc + dq;
#pragma unroll
        for (int c = 0; c < 8; ++c) {
            *(float4*)&out_k[o + c * 4] = *(float4*)&ko[c * 4];
            *(float4*)&out_v[o + c * 4] = *(float4*)&vo[c * 4];
        }
        size_t fb = ((size_t)b * NQc + hq) * ((size_t)Tc * Dc);
#pragma unroll
        for (int g = 0; g < 4; ++g)
            *(uint4*)&kfr[fb + (size_t)(((t16 * 4 + dc) * 4 + g) * 128 + lnr * 8)] = *(uint4*)&kbf[g * 8];
    }
    // LDS transpose of v -> vfr subtiles (replicated over the 4 q-heads)
#pragma unroll
    for (int c = 0; c < 4; ++c) *(uint4*)&Vl[tt][dq + c * 8] = *(uint4*)&vb[c * 8];
    __syncthreads();
    const int tile = 16 + sb;
#pragma unroll
    for (int i = 0; i < 4; ++i) {
        int u = i * 256 + tid;
        int d = u >> 3, cc = u & 7;
        bf16_t tmp[8];
#pragma unroll
        for (int j = 0; j < 8; ++j) tmp[j] = Vl[cc * 8 + j][d];
        size_t off = (size_t)((((tile * 8 + (d >> 4)) * 2 + (cc >> 2)) * 4 + (cc & 3)) * 128 + (d & 15) * 8);
#pragma unroll
        for (int gg = 0; gg < 4; ++gg) {
            int hq = hk * 4 + gg;
            size_t fb = ((size_t)b * NQc + hq) * ((size_t)Tc * Dc);
            *(uint4*)&vfr[fb + off] = *(uint4*)tmp;
        }
    }
}

// ---------------- cache copy + frag layouts (ALL 32 heads independent) ------
// grid (tb=16, h=32, b=2), 256 threads
__global__ __launch_bounds__(256) void k_cache(const float* __restrict__ kc,
                                               const float* __restrict__ vc,
                                               float* __restrict__ out_k,
                                               float* __restrict__ out_v,
                                               bf16_t* __restrict__ kfr,
                                               bf16_t* __restrict__ vfr) {
    __shared__ __align__(16) bf16_t Vl[64][136];
    const int tb = blockIdx.x, h = blockIdx.y, b = blockIdx.z;
    const int tid = threadIdx.x;
    const int tt = tid >> 2, dq = (tid & 3) * 32;
    const int t = tb * 64 + tt;
    size_t src = ((size_t)(b * OFFc + t) * NQc + h) * Dc + dq;
    size_t dst = ((size_t)(b * Tc + t) * NQc + h) * Dc + dq;
    const size_t fb = ((size_t)b * NQc + h) * ((size_t)Tc * Dc);

    bf16_t kb[32], vb[32];
#pragma unroll
    for (int c = 0; c < 8; ++c) {
        float4 kv = *(const float4*)&kc[src + c * 4];
        *(float4*)&out_k[dst + c * 4] = kv;
        kb[c * 4] = (bf16_t)kv.x; kb[c * 4 + 1] = (bf16_t)kv.y;
        kb[c * 4 + 2] = (bf16_t)kv.z; kb[c * 4 + 3] = (bf16_t)kv.w;
        float4 vv = *(const float4*)&vc[src + c * 4];
        *(float4*)&out_v[dst + c * 4] = vv;
        vb[c * 4] = (bf16_t)vv.x; vb[c * 4 + 1] = (bf16_t)vv.y;
        vb[c * 4 + 2] = (bf16_t)vv.z; vb[c * 4 + 3] = (bf16_t)vv.w;
    }
    const int t16 = t >> 4, lnr = t & 15, dc = dq >> 5;
#pragma unroll
    for (int g = 0; g < 4; ++g)
        *(uint4*)&kfr[fb + (size_t)(((t16 * 4 + dc) * 4 + g) * 128 + lnr * 8)] = *(uint4*)&kb[g * 8];

#pragma unroll
    for (int c = 0; c < 4; ++c) *(uint4*)&Vl[tt][dq + c * 8] = *(uint4*)&vb[c * 8];
    __syncthreads();
#pragma unroll
    for (int i = 0; i < 4; ++i) {
        int u = i * 256 + tid;
        int d = u >> 3, cc = u & 7;
        bf16_t tmp[8];
#pragma unroll
        for (int j = 0; j < 8; ++j) tmp[j] = Vl[cc * 8 + j][d];
        size_t off = (size_t)((((tb * 8 + (d >> 4)) * 2 + (cc >> 2)) * 4 + (cc & 3)) * 128 + (d & 15) * 8);
        *(uint4*)&vfr[fb + off] = *(uint4*)tmp;
    }
}

// ---------------- flash attention v5: 8 waves + swapped QK^T ----------------
// 256 blocks x 512 threads (8 waves x 32 q-rows = 256 q-rows/block).
// K/V LDS-staged double-buffered (64KB, R8-proven); swapped mfma(K,Q) gives a
// full P-row per lane: in-lane max/sum + 2 shfl, P stored as 8 b64 writes per
// tile into pad-72 rows (no swizzle needed), PV A-frags read as b128.
__global__ __launch_bounds__(512) void k_attn(const bf16_t* __restrict__ qkv,
                                              const bf16_t* __restrict__ kfr,
                                              const bf16_t* __restrict__ vfr,
                                              bf16_t* __restrict__ attn) {
    __shared__ __align__(16) bf16_t Kl[2][8192];   // 32 KB
    __shared__ __align__(16) bf16_t Vl2[2][8192];  // 32 KB
    __shared__ __align__(16) bf16_t Pl[8][32 * 72];// 36 KB (pad-72 rows)
    const int tid = threadIdx.x, w = tid >> 6, l = tid & 63;
    const int g = l >> 4, ln = l & 15;
    const int bid = blockIdx.x;
    const int xcd = bid & 7, within = bid >> 3;    // 0..31
    const int qblk = 3 - (within & 3);             // longest q-blocks first
    const int u = within >> 2;                     // 0..7
    const int b = u >> 2;
    const int h = (u & 3) * 8 + xcd;
    const int q0b = qblk * 256;
    const int qw0 = q0b + w * 32;
    const float SCALE = 0.08838834764831845f;
    const float L2E = 1.4426950408889634f;
    const size_t hb = ((size_t)b * NQc + h) * ((size_t)Tc * Dc);
    const bf16_t* kb = kfr + hb;
    const bf16_t* vb = vfr + hb;
    bf16_t* Pw = &Pl[w][0];

    bf16x8 qf[2][4];
#pragma unroll
    for (int mf = 0; mf < 2; ++mf) {
        size_t qrow = (size_t)(b * Sc + qw0 + mf * 16 + ln) * NQKV + h * Dc;
#pragma unroll
        for (int dc = 0; dc < 4; ++dc) qf[mf][dc] = *(const bf16x8*)&qkv[qrow + dc * 32 + g * 8];
    }
    f32x4 o[2][8] = {};
    float mrun[2] = {-1e30f, -1e30f};   // per lane: row q = mf*16 + ln
    float lrun[2] = {0.f, 0.f};

    const int ntiles = (OFFc + q0b + 256) >> 6;    // block covers tokens < OFF+q0b+256

    // stage tile t into buffer bf: each wave copies its 2 chunks of K and V
    auto stage = [&](int bf, int t) {
        const bf16_t* ksrc = kb + (size_t)t * 8192 + (size_t)(w * 2) * 512;
        const bf16_t* vsrc = vb + (size_t)t * 8192 + (size_t)(w * 2) * 512;
        load_lds16(ksrc + (size_t)l * 8,       &Kl[bf][(w * 2) * 512]);
        load_lds16(ksrc + 512 + (size_t)l * 8, &Kl[bf][(w * 2 + 1) * 512]);
        load_lds16(vsrc + (size_t)l * 8,       &Vl2[bf][(w * 2) * 512]);
        load_lds16(vsrc + 512 + (size_t)l * 8, &Vl2[bf][(w * 2 + 1) * 512]);
    };

    stage(0, 0);
    __syncthreads();
    int cur = 0;

    for (int t = 0; t < ntiles; ++t) {
        if (t + 1 < ntiles) stage(cur ^ 1, t + 1);
        // ---- QK^T (swapped): lane (g,ln) holds S[t=nf*16+g*4+r][q=mf*16+ln] ----
        f32x4 sa[2][4] = {};
#pragma unroll
        for (int nf = 0; nf < 4; ++nf) {
            bf16x8 kf[4];
#pragma unroll
            for (int dc = 0; dc < 4; ++dc)
                kf[dc] = *(const bf16x8*)&Kl[cur][((nf * 4 + dc) * 4 + g) * 128 + ln * 8];
#pragma unroll
            for (int dc = 0; dc < 4; ++dc) {
                sa[0][nf] = __builtin_amdgcn_mfma_f32_16x16x32_bf16(kf[dc], qf[0][dc], sa[0][nf], 0, 0, 0);
                sa[1][nf] = __builtin_amdgcn_mfma_f32_16x16x32_bf16(kf[dc], qf[1][dc], sa[1][nf], 0, 0, 0);
            }
        }
        // ---- scale + causal mask ----
        bool maybe = (t * 64 + 63 > OFFc + qw0);
#pragma unroll
        for (int mf = 0; mf < 2; ++mf)
#pragma unroll
            for (int nf = 0; nf < 4; ++nf)
#pragma unroll
                for (int r = 0; r < 4; ++r) {
                    float s = sa[mf][nf][r] * SCALE;
                    if (maybe) {
                        int tg = t * 64 + nf * 16 + g * 4 + r;
                        int qg = qw0 + mf * 16 + ln;
                        if (tg > OFFc + qg) s = -1e30f;
                    }
                    sa[mf][nf][r] = s;
                }
        // ---- row max (15 in-lane + 2 shfl) + exact skip-rescale ----
        float tm[2];
        int grew = 0;
#pragma unroll
        for (int mf = 0; mf < 2; ++mf) {
            float m2 = sa[mf][0][0];
#pragma unroll
            for (int nf = 0; nf < 4; ++nf)
#pragma unroll
                for (int r = 0; r < 4; ++r) m2 = fmaxf(m2, sa[mf][nf][r]);
            m2 = fmaxf(m2, __shfl_xor(m2, 16));
            m2 = fmaxf(m2, __shfl_xor(m2, 32));
            tm[mf] = m2;
            grew |= (m2 > mrun[mf]) ? 1 : 0;
        }
        if (__any(grew)) {
#pragma unroll
            for (int mf = 0; mf < 2; ++mf) {
                float mn = fmaxf(mrun[mf], tm[mf]);
                float al = exp2f((mrun[mf] - mn) * L2E);
                mrun[mf] = mn;
                lrun[mf] *= al;
                // redistribute al (per q=mf*16+ln) to PV row layout q=mf*16+g*4+r
                float alr[4];
#pragma unroll
                for (int r = 0; r < 4; ++r)
                    alr[r] = __shfl(al, (l & 48) | (g * 4 + r));
#pragma unroll
                for (int df = 0; df < 8; ++df) {
                    f32x4 t4 = o[mf][df];
                    t4[0] *= alr[0]; t4[1] *= alr[1]; t4[2] *= alr[2]; t4[3] *= alr[3];
                    o[mf][df] = t4;
                }
            }
        }
        // ---- P = exp (in-lane), l-sum, linear b64 P-store (pad-72 rows) ----
#pragma unroll
        for (int mf = 0; mf < 2; ++mf) {
            const int qrow = mf * 16 + ln;
            float ps = 0.f;
#pragma unroll
            for (int nf = 0; nf < 4; ++nf) {
                bf16_t pv[4];
#pragma unroll
                for (int r = 0; r < 4; ++r) {
                    float p = exp2f((sa[mf][nf][r] - mrun[mf]) * L2E);
                    ps += p;
                    pv[r] = (bf16_t)p;
                }
                *(uint2*)&Pw[qrow * 72 + nf * 16 + g * 4] = *(uint2*)pv;
            }
            ps += __shfl_xor(ps, 16);
            ps += __shfl_xor(ps, 32);
            lrun[mf] += ps;
        }
        // ---- PV from LDS V tile: kc halves sequentially ----
#pragma unroll
        for (int kc = 0; kc < 2; ++kc) {
            bf16x8 vf[8];
#pragma unroll
            for (int df = 0; df < 8; ++df)
                vf[df] = *(const bf16x8*)&Vl2[cur][((df * 2 + kc) * 4 + g) * 128 + ln * 8];
#pragma unroll
            for (int mf = 0; mf < 2; ++mf) {
                bf16x8 pa = *(const bf16x8*)&Pw[(mf * 16 + ln) * 72 + kc * 32 + g * 8];
#pragma unroll
                for (int df = 0; df < 8; ++df)
                    o[mf][df] = __builtin_amdgcn_mfma_f32_16x16x32_bf16(pa, vf[df], o[mf][df], 0, 0, 0);
            }
        }
        __syncthreads();   // drains staged loads for t+1; guards buffer reuse
        cur ^= 1;
    }

    // epilogue: o rows are q = qw0 + mf*16 + g*4 + r; 1/l fetched via shfl
#pragma unroll
    for (int mf = 0; mf < 2; ++mf) {
        float linv[4];
#pragma unroll
        for (int r = 0; r < 4; ++r)
            linv[r] = 1.f / __shfl(lrun[mf], (l & 48) | (g * 4 + r));
#pragma unroll
        for (int df = 0; df < 8; ++df)
#pragma unroll
            for (int r = 0; r < 4; ++r) {
                float v = o[mf][df][r] * linv[r];
                size_t orow = (size_t)(b * Sc + qw0 + mf * 16 + g * 4 + r) * (NQc * Dc) + h * Dc + df * 16 + ln;
                attn[orow] = (bf16_t)v;
            }
    }
}

extern "C" void kernel_launch(void* const* d_in, const int* in_sizes, int n_in,
                              void* d_out, int out_size, void* d_ws, size_t ws_size,
                              hipStream_t stream) {
    const float* x      = (const float*)d_in[0];
    const float* cosT   = (const float*)d_in[2];
    const float* sinT   = (const float*)d_in[3];
    const float* kcache = (const float*)d_in[4];
    const float* vcache = (const float*)d_in[5];
    const float* q_w    = (const float*)d_in[6];
    const float* q_b    = (const float*)d_in[7];
    const float* k_w    = (const float*)d_in[8];
    const float* k_b    = (const float*)d_in[9];
    const float* v_w    = (const float*)d_in[10];
    const float* v_b    = (const float*)d_in[11];
    const float* o_w    = (const float*)d_in[12];

    char* ws = (char*)d_ws;
    size_t off = 0;
    auto alloc = [&](size_t bytes) {
        void* p = ws + off;
        off += (bytes + 255) & ~(size_t)255;
        return p;
    };
    bf16_t* xb   = (bf16_t*)alloc((size_t)Mrows * HIDc * 2);        // reused as attn out
    bf16_t* wqkv = (bf16_t*)alloc((size_t)Bc * Tc * NQc * Dc * 4);  // reused as kfr+vfr
    bf16_t* owb  = (bf16_t*)alloc((size_t)HIDc * HIDc * 2);
    bf16_t* qkv  = (bf16_t*)alloc((size_t)Mrows * NQKV * 2);
    float*  bias = (float*)alloc((size_t)NQKV * 4);
    if (off > ws_size) {
        fprintf(stderr, "WS too small: need %zu have %zu\n", off, ws_size);
        return;
    }
    bf16_t* attn  = xb;
    bf16_t* kfr = wqkv;                                   // 33.55 MB per-head frags
    bf16_t* vfr = wqkv + (size_t)Bc * NQc * Tc * Dc;      // 33.55 MB

    float* out_o = (float*)d_out;
    float* out_k = out_o + (size_t)Mrows * HIDc;
    float* out_v = out_k + (size_t)Bc * Tc * NQc * Dc;

    k_cvt<<<2048, 256, 0, stream>>>(x, xb, (long)Mrows * HIDc / 4);
    k_cvt<<<2048, 256, 0, stream>>>(q_w, wqkv, (long)NQc * Dc * HIDc / 4);
    k_cvt<<<1024, 256, 0, stream>>>(k_w, wqkv + (size_t)NQc * Dc * HIDc, (long)NKVc * Dc * HIDc / 4);
    k_cvt<<<1024, 256, 0, stream>>>(v_w, wqkv + (size_t)(NQc + NKVc) * Dc * HIDc, (long)NKVc * Dc * HIDc / 4);
    k_cvt<<<2048, 256, 0, stream>>>(o_w, owb, (long)HIDc * HIDc / 4);
    (void)hipMemcpyAsync(bias, q_b, (size_t)NQc * Dc * 4, hipMemcpyDeviceToDevice, stream);
    (void)hipMemcpyAsync(bias + NQc * Dc, k_b, (size_t)NKVc * Dc * 4, hipMemcpyDeviceToDevice, stream);
    (void)hipMemcpyAsync(bias + (NQc + NKVc) * Dc, v_b, (size_t)NKVc * Dc * 4, hipMemcpyDeviceToDevice, stream);

    k_gemm<true, true><<<dim3(NQKV / 128, Mrows / 128), 256, 0, stream>>>(
        xb, wqkv, bias, qkv, Mrows, NQKV, HIDc);
    // weights in wqkv are dead after this GEMM; kfr/vfr alias the region and
    // are written only by stream-ordered later kernels.
    k_rope_q<<<Mrows, 256, 0, stream>>>(qkv, cosT, sinT);
    k_ropekv<<<dim3(16, 8, 2), 256, 0, stream>>>(qkv, cosT, sinT, out_k, out_v, kfr, vfr);
    k_cache<<<dim3(16, 32, 2), 256, 0, stream>>>(kcache, vcache, out_k, out_v, kfr, vfr);
    k_attn<<<256, 512, 0, stream>>>(qkv, kfr, vfr, attn);
    k_gemm<false, false><<<dim3(HIDc / 128, Mrows / 128), 256, 0, stream>>>(
        attn, owb, nullptr, d_out, Mrows, HIDc, HIDc);
}

// Round 16
// 470.283 us; speedup vs baseline: 1.1043x; 1.0660x over previous
//
#include <hip/hip_runtime.h>
#include <hip/hip_bf16.h>
#include <cstdio>
#include <cstdint>

typedef __bf16 bf16_t;
typedef __bf16 bf16x8 __attribute__((ext_vector_type(8)));
typedef float f32x4 __attribute__((ext_vector_type(4)));

static constexpr int Bc = 2, Sc = 1024, HIDc = 4096;
static constexpr int NQc = 32, NKVc = 8, Dc = 128, OFFc = 1024, Tc = 2048;
static constexpr int Mrows = Bc * Sc;                 // 2048
static constexpr int NQKV = (NQc + 2 * NKVc) * Dc;    // 6144

__device__ inline void load_lds16(const void* g, void* l) {
    __builtin_amdgcn_global_load_lds(
        (const __attribute__((address_space(1))) unsigned*)g,
        (__attribute__((address_space(3))) unsigned*)l, 16, 0, 0);
}

// ---------------- fused fp32 -> bf16 convert (5 segments, 1 launch) --------
__global__ void k_cvt5(const float* __restrict__ s0, const float* __restrict__ s1,
                       const float* __restrict__ s2, const float* __restrict__ s3,
                       const float* __restrict__ s4,
                       bf16_t* __restrict__ d0, bf16_t* __restrict__ d1,
                       bf16_t* __restrict__ d2, bf16_t* __restrict__ d3,
                       bf16_t* __restrict__ d4,
                       long c0, long c1, long c2, long c3, long c4) {
    long i = blockIdx.x * (long)blockDim.x + threadIdx.x;
    long stride = (long)gridDim.x * blockDim.x;
    for (; i < c4; i += stride) {
        const float* src; bf16_t* dst; long j;
        if (i < c0)      { src = s0; dst = d0; j = i; }
        else if (i < c1) { src = s1; dst = d1; j = i - c0; }
        else if (i < c2) { src = s2; dst = d2; j = i - c1; }
        else if (i < c3) { src = s3; dst = d3; j = i - c2; }
        else             { src = s4; dst = d4; j = i - c3; }
        float4 v = *(const float4*)&src[j * 4];
        bf16_t t[4] = {(bf16_t)v.x, (bf16_t)v.y, (bf16_t)v.z, (bf16_t)v.w};
        *(uint2*)&dst[j * 4] = *(uint2*)t;
    }
}

// ---------------- GEMM (m97 structure, BK=64, bank-spread swizzle) ----------
// C[M][N] = A[M][K] * B[N][K]^T (+bias). BMx128 tile, BK=64, 4 waves (2x2),
// global_load_lds w16, bijective XCD swizzle. Rows are 8x16B units (128B =
// 32 banks); involution swizzle LDS[row][u] = G[row][u ^ (row&7)] (linear
// dest, pre-swizzled source; same XOR on read) -> conflict-free frag reads.
// BM=128 for QKV (768 blocks, 3/CU); BM=64 for O-proj (1024 blocks, 4/CU —
// resident-block count is the latency-hiding currency, R15 post-mortem).
template <int BM, bool BIAS, bool OUT_BF16>
__global__ __launch_bounds__(256) void k_gemm(const bf16_t* __restrict__ A,
                                              const bf16_t* __restrict__ Bm,
                                              const float* __restrict__ bias,
                                              void* __restrict__ Cout,
                                              int M, int N, int K) {
    constexpr int MI = BM / 32;          // m-frags per wave
    __shared__ __align__(16) bf16_t As[BM][64];
    __shared__ __align__(16) bf16_t Bs[128][64];
    const int tid = threadIdx.x, wid = tid >> 6, lane = tid & 63;
    const int g = lane >> 4, ln = lane & 15;
    const int wm = wid >> 1, wn = wid & 1;
    const int gx = gridDim.x;
    int bidl = blockIdx.y * gx + blockIdx.x;
    int cpx = (gx * gridDim.y) >> 3;
    int swz = (bidl & 7) * cpx + (bidl >> 3);
    const int m0 = (swz / gx) * BM, n0 = (swz % gx) * 128;
    f32x4 acc[MI][4] = {};

    for (int k0 = 0; k0 < K; k0 += 64) {
        __syncthreads();
#pragma unroll
        for (int c = 0; c < BM / 32; ++c) {
            int row = wid * (BM / 4) + c * 8 + (lane >> 3);
            int col = ((lane & 7) ^ (row & 7)) * 8;    // pre-swizzled source unit
            load_lds16(A + (size_t)(m0 + row) * K + k0 + col, &As[wid * (BM / 4) + c * 8][0]);
        }
#pragma unroll
        for (int c = 0; c < 4; ++c) {
            int row = wid * 32 + c * 8 + (lane >> 3);
            int col = ((lane & 7) ^ (row & 7)) * 8;
            load_lds16(Bm + (size_t)(n0 + row) * K + k0 + col, &Bs[wid * 32 + c * 8][0]);
        }
        __syncthreads();
#pragma unroll
        for (int kk = 0; kk < 2; ++kk) {
            bf16x8 af[MI], bfr[4];
#pragma unroll
            for (int i = 0; i < MI; ++i) {
                int row = wm * (BM / 2) + i * 16 + ln;
                af[i] = *(const bf16x8*)&As[row][(((kk * 4 + g) ^ (row & 7)) * 8)];
            }
#pragma unroll
            for (int j = 0; j < 4; ++j) {
                int row = wn * 64 + j * 16 + ln;
                bfr[j] = *(const bf16x8*)&Bs[row][(((kk * 4 + g) ^ (row & 7)) * 8)];
            }
#pragma unroll
            for (int i = 0; i < MI; ++i)
#pragma unroll
                for (int j = 0; j < 4; ++j)
                    acc[i][j] = __builtin_amdgcn_mfma_f32_16x16x32_bf16(af[i], bfr[j], acc[i][j], 0, 0, 0);
        }
    }

#pragma unroll
    for (int i = 0; i < MI; ++i) {
#pragma unroll
        for (int j = 0; j < 4; ++j) {
            int col = n0 + wn * 64 + j * 16 + ln;
            float bv = BIAS ? bias[col] : 0.f;
#pragma unroll
            for (int r = 0; r < 4; ++r) {
                int row = m0 + wm * (BM / 2) + i * 16 + g * 4 + r;
                float v = acc[i][j][r] + bv;
                if (OUT_BF16)
                    ((bf16_t*)Cout)[(size_t)row * N + col] = (bf16_t)v;
                else
                    ((float*)Cout)[(size_t)row * N + col] = v;
            }
        }
    }
}

// ---------------- RoPE q in place ----------------
__global__ void k_rope_q(bf16_t* __restrict__ qkv, const float* __restrict__ cosT,
                         const float* __restrict__ sinT) {
    int row = blockIdx.x;            // 0..2047 = b*1024 + s
    int s = row & 1023;
    bf16_t* src = qkv + (size_t)row * NQKV;
    for (int p = threadIdx.x; p < 2048; p += 256) {
        int j = p & 63;
        float c = cosT[s * 64 + j], sn = sinT[s * 64 + j];
        float xr = (float)src[2 * p], xi = (float)src[2 * p + 1];
        src[2 * p]     = (bf16_t)(xr * c - xi * sn);
        src[2 * p + 1] = (bf16_t)(xr * sn + xi * c);
    }
}

// Frag layouts PER Q-HEAD (b,h), flat size Tc*Dc each. Each 64-token tile t
// occupies the CONTIGUOUS elem range [t*8192, (t+1)*8192):
//  kfr: idx(t,d) = ((t16*4+dc)*4+g)*128 + ln*8 + e   [t16=t>>4, ln=t&15; dc=d>>5, g=(d>>3)&3, e=d&7]
//  vfr: idx(t,d) = (((tile*8+d16)*2+kc)*4+gk)*128 + ln*8 + e
//       [tile=t>>6, kc=(t>>5)&1, gk=(t>>3)&3, e=t&7; d16=d>>4, ln=d&15]

// ---------------- RoPE k + scatter new K/V ----------------
// grid (sb=16, hk=8, b=2), 256 threads
__global__ __launch_bounds__(256) void k_ropekv(const bf16_t* __restrict__ qkv,
                                                const float* __restrict__ cosT,
                                                const float* __restrict__ sinT,
                                                float* __restrict__ out_k,
                                                float* __restrict__ out_v,
                                                bf16_t* __restrict__ kfr,
                                                bf16_t* __restrict__ vfr) {
    __shared__ __align__(16) bf16_t Vl[64][136];
    const int sb = blockIdx.x, hk = blockIdx.y, b = blockIdx.z;
    const int tid = threadIdx.x;
    const int tt = tid >> 2, dq = (tid & 3) * 32;
    const int s = sb * 64 + tt;
    const int t = OFFc + s;
    const bf16_t* krow = qkv + (size_t)(b * Sc + s) * NQKV + NQc * Dc + hk * Dc + dq;
    const bf16_t* vrow = qkv + (size_t)(b * Sc + s) * NQKV + (NQc + NKVc) * Dc + hk * Dc + dq;

    float cs[16], sn[16];
    int j0 = dq >> 1;
#pragma unroll
    for (int q4 = 0; q4 < 4; ++q4) {
        float4 cv = *(const float4*)&cosT[s * 64 + j0 + q4 * 4];
        float4 sv = *(const float4*)&sinT[s * 64 + j0 + q4 * 4];
        cs[q4 * 4] = cv.x; cs[q4 * 4 + 1] = cv.y; cs[q4 * 4 + 2] = cv.z; cs[q4 * 4 + 3] = cv.w;
        sn[q4 * 4] = sv.x; sn[q4 * 4 + 1] = sv.y; sn[q4 * 4 + 2] = sv.z; sn[q4 * 4 + 3] = sv.w;
    }

    bf16_t kb[32], vb[32];
#pragma unroll
    for (int c = 0; c < 4; ++c) {
        *(uint4*)&kb[c * 8] = *(const uint4*)&krow[c * 8];
        *(uint4*)&vb[c * 8] = *(const uint4*)&vrow[c * 8];
    }
    float ko[32], vo[32];
    bf16_t kbf[32];
#pragma unroll
    for (int jj = 0; jj < 16; ++jj) {
        float xr = (float)kb[2 * jj], xi = (float)kb[2 * jj + 1];
        ko[2 * jj]     = xr * cs[jj] - xi * sn[jj];
        ko[2 * jj + 1] = xr * sn[jj] + xi * cs[jj];
        kbf[2 * jj]     = (bf16_t)ko[2 * jj];
        kbf[2 * jj + 1] = (bf16_t)ko[2 * jj + 1];
        vo[2 * jj] = (float)vb[2 * jj];
        vo[2 * jj + 1] = (float)vb[2 * jj + 1];
    }

    const int t16 = t >> 4, lnr = t & 15, dc = dq >> 5;
#pragma unroll
    for (int gg = 0; gg < 4; ++gg) {
        int hq = hk * 4 + gg;
        size_t o = ((size_t)(b * Tc + t) * NQc + hq) * Dc + dq;
#pragma unroll
        for (int c = 0; c < 8; ++c) {
            *(float4*)&out_k[o + c * 4] = *(float4*)&ko[c * 4];
            *(float4*)&out_v[o + c * 4] = *(float4*)&vo[c * 4];
        }
        size_t fb = ((size_t)b * NQc + hq) * ((size_t)Tc * Dc);
#pragma unroll
        for (int g = 0; g < 4; ++g)
            *(uint4*)&kfr[fb + (size_t)(((t16 * 4 + dc) * 4 + g) * 128 + lnr * 8)] = *(uint4*)&kbf[g * 8];
    }
    // LDS transpose of v -> vfr subtiles (replicated over the 4 q-heads)
#pragma unroll
    for (int c = 0; c < 4; ++c) *(uint4*)&Vl[tt][dq + c * 8] = *(uint4*)&vb[c * 8];
    __syncthreads();
    const int tile = 16 + sb;
#pragma unroll
    for (int i = 0; i < 4; ++i) {
        int u = i * 256 + tid;
        int d = u >> 3, cc = u & 7;
        bf16_t tmp[8];
#pragma unroll
        for (int j = 0; j < 8; ++j) tmp[j] = Vl[cc * 8 + j][d];
        size_t off = (size_t)((((tile * 8 + (d >> 4)) * 2 + (cc >> 2)) * 4 + (cc & 3)) * 128 + (d & 15) * 8);
#pragma unroll
        for (int gg = 0; gg < 4; ++gg) {
            int hq = hk * 4 + gg;
            size_t fb = ((size_t)b * NQc + hq) * ((size_t)Tc * Dc);
            *(uint4*)&vfr[fb + off] = *(uint4*)tmp;
        }
    }
}

// ---------------- cache copy + frag layouts (ALL 32 heads independent) ------
// grid (tb=16, h=32, b=2), 256 threads
__global__ __launch_bounds__(256) void k_cache(const float* __restrict__ kc,
                                               const float* __restrict__ vc,
                                               float* __restrict__ out_k,
                                               float* __restrict__ out_v,
                                               bf16_t* __restrict__ kfr,
                                               bf16_t* __restrict__ vfr) {
    __shared__ __align__(16) bf16_t Vl[64][136];
    const int tb = blockIdx.x, h = blockIdx.y, b = blockIdx.z;
    const int tid = threadIdx.x;
    const int tt = tid >> 2, dq = (tid & 3) * 32;
    const int t = tb * 64 + tt;
    size_t src = ((size_t)(b * OFFc + t) * NQc + h) * Dc + dq;
    size_t dst = ((size_t)(b * Tc + t) * NQc + h) * Dc + dq;
    const size_t fb = ((size_t)b * NQc + h) * ((size_t)Tc * Dc);

    bf16_t kb[32], vb[32];
#pragma unroll
    for (int c = 0; c < 8; ++c) {
        float4 kv = *(const float4*)&kc[src + c * 4];
        *(float4*)&out_k[dst + c * 4] = kv;
        kb[c * 4] = (bf16_t)kv.x; kb[c * 4 + 1] = (bf16_t)kv.y;
        kb[c * 4 + 2] = (bf16_t)kv.z; kb[c * 4 + 3] = (bf16_t)kv.w;
        float4 vv = *(const float4*)&vc[src + c * 4];
        *(float4*)&out_v[dst + c * 4] = vv;
        vb[c * 4] = (bf16_t)vv.x; vb[c * 4 + 1] = (bf16_t)vv.y;
        vb[c * 4 + 2] = (bf16_t)vv.z; vb[c * 4 + 3] = (bf16_t)vv.w;
    }
    const int t16 = t >> 4, lnr = t & 15, dc = dq >> 5;
#pragma unroll
    for (int g = 0; g < 4; ++g)
        *(uint4*)&kfr[fb + (size_t)(((t16 * 4 + dc) * 4 + g) * 128 + lnr * 8)] = *(uint4*)&kb[g * 8];

#pragma unroll
    for (int c = 0; c < 4; ++c) *(uint4*)&Vl[tt][dq + c * 8] = *(uint4*)&vb[c * 8];
    __syncthreads();
#pragma unroll
    for (int i = 0; i < 4; ++i) {
        int u = i * 256 + tid;
        int d = u >> 3, cc = u & 7;
        bf16_t tmp[8];
#pragma unroll
        for (int j = 0; j < 8; ++j) tmp[j] = Vl[cc * 8 + j][d];
        size_t off = (size_t)((((tb * 8 + (d >> 4)) * 2 + (cc >> 2)) * 4 + (cc & 3)) * 128 + (d & 15) * 8);
        *(uint4*)&vfr[fb + off] = *(uint4*)tmp;
    }
}

// ---------------- flash attention v5: 8 waves + swapped QK^T ----------------
// 256 blocks x 512 threads (8 waves x 32 q-rows = 256 q-rows/block).
// K/V LDS-staged double-buffered (64KB, R8-proven); swapped mfma(K,Q) gives a
// full P-row per lane: in-lane max/sum + 2 shfl, P stored as 8 b64 writes per
// tile into pad-72 rows (no swizzle needed), PV A-frags read as b128.
__global__ __launch_bounds__(512) void k_attn(const bf16_t* __restrict__ qkv,
                                              const bf16_t* __restrict__ kfr,
                                              const bf16_t* __restrict__ vfr,
                                              bf16_t* __restrict__ attn) {
    __shared__ __align__(16) bf16_t Kl[2][8192];   // 32 KB
    __shared__ __align__(16) bf16_t Vl2[2][8192];  // 32 KB
    __shared__ __align__(16) bf16_t Pl[8][32 * 72];// 36 KB (pad-72 rows)
    const int tid = threadIdx.x, w = tid >> 6, l = tid & 63;
    const int g = l >> 4, ln = l & 15;
    const int bid = blockIdx.x;
    const int xcd = bid & 7, within = bid >> 3;    // 0..31
    const int qblk = 3 - (within & 3);             // longest q-blocks first
    const int u = within >> 2;                     // 0..7
    const int b = u >> 2;
    const int h = (u & 3) * 8 + xcd;
    const int q0b = qblk * 256;
    const int qw0 = q0b + w * 32;
    const float SCALE = 0.08838834764831845f;
    const float L2E = 1.4426950408889634f;
    const size_t hb = ((size_t)b * NQc + h) * ((size_t)Tc * Dc);
    const bf16_t* kb = kfr + hb;
    const bf16_t* vb = vfr + hb;
    bf16_t* Pw = &Pl[w][0];

    bf16x8 qf[2][4];
#pragma unroll
    for (int mf = 0; mf < 2; ++mf) {
        size_t qrow = (size_t)(b * Sc + qw0 + mf * 16 + ln) * NQKV + h * Dc;
#pragma unroll
        for (int dc = 0; dc < 4; ++dc) qf[mf][dc] = *(const bf16x8*)&qkv[qrow + dc * 32 + g * 8];
    }
    f32x4 o[2][8] = {};
    float mrun[2] = {-1e30f, -1e30f};   // per lane: row q = mf*16 + ln
    float lrun[2] = {0.f, 0.f};

    const int ntiles = (OFFc + q0b + 256) >> 6;    // block covers tokens < OFF+q0b+256

    // stage tile t into buffer bf: each wave copies its 2 chunks of K and V
    auto stage = [&](int bf, int t) {
        const bf16_t* ksrc = kb + (size_t)t * 8192 + (size_t)(w * 2) * 512;
        const bf16_t* vsrc = vb + (size_t)t * 8192 + (size_t)(w * 2) * 512;
        load_lds16(ksrc + (size_t)l * 8,       &Kl[bf][(w * 2) * 512]);
        load_lds16(ksrc + 512 + (size_t)l * 8, &Kl[bf][(w * 2 + 1) * 512]);
        load_lds16(vsrc + (size_t)l * 8,       &Vl2[bf][(w * 2) * 512]);
        load_lds16(vsrc + 512 + (size_t)l * 8, &Vl2[bf][(w * 2 + 1) * 512]);
    };

    stage(0, 0);
    __syncthreads();
    int cur = 0;

    for (int t = 0; t < ntiles; ++t) {
        if (t + 1 < ntiles) stage(cur ^ 1, t + 1);
        // ---- QK^T (swapped): lane (g,ln) holds S[t=nf*16+g*4+r][q=mf*16+ln] ----
        f32x4 sa[2][4] = {};
#pragma unroll
        for (int nf = 0; nf < 4; ++nf) {
            bf16x8 kf[4];
#pragma unroll
            for (int dc = 0; dc < 4; ++dc)
                kf[dc] = *(const bf16x8*)&Kl[cur][((nf * 4 + dc) * 4 + g) * 128 + ln * 8];
#pragma unroll
            for (int dc = 0; dc < 4; ++dc) {
                sa[0][nf] = __builtin_amdgcn_mfma_f32_16x16x32_bf16(kf[dc], qf[0][dc], sa[0][nf], 0, 0, 0);
                sa[1][nf] = __builtin_amdgcn_mfma_f32_16x16x32_bf16(kf[dc], qf[1][dc], sa[1][nf], 0, 0, 0);
            }
        }
        // ---- scale + causal mask ----
        bool maybe = (t * 64 + 63 > OFFc + qw0);
#pragma unroll
        for (int mf = 0; mf < 2; ++mf)
#pragma unroll
            for (int nf = 0; nf < 4; ++nf)
#pragma unroll
                for (int r = 0; r < 4; ++r) {
                    float s = sa[mf][nf][r] * SCALE;
                    if (maybe) {
                        int tg = t * 64 + nf * 16 + g * 4 + r;
                        int qg = qw0 + mf * 16 + ln;
                        if (tg > OFFc + qg) s = -1e30f;
                    }
                    sa[mf][nf][r] = s;
                }
        // ---- row max (15 in-lane + 2 shfl) + exact skip-rescale ----
        float tm[2];
        int grew = 0;
#pragma unroll
        for (int mf = 0; mf < 2; ++mf) {
            float m2 = sa[mf][0][0];
#pragma unroll
            for (int nf = 0; nf < 4; ++nf)
#pragma unroll
                for (int r = 0; r < 4; ++r) m2 = fmaxf(m2, sa[mf][nf][r]);
            m2 = fmaxf(m2, __shfl_xor(m2, 16));
            m2 = fmaxf(m2, __shfl_xor(m2, 32));
            tm[mf] = m2;
            grew |= (m2 > mrun[mf]) ? 1 : 0;
        }
        if (__any(grew)) {
#pragma unroll
            for (int mf = 0; mf < 2; ++mf) {
                float mn = fmaxf(mrun[mf], tm[mf]);
                float al = exp2f((mrun[mf] - mn) * L2E);
                mrun[mf] = mn;
                lrun[mf] *= al;
                // redistribute al (per q=mf*16+ln) to PV row layout q=mf*16+g*4+r
                float alr[4];
#pragma unroll
                for (int r = 0; r < 4; ++r)
                    alr[r] = __shfl(al, (l & 48) | (g * 4 + r));
#pragma unroll
                for (int df = 0; df < 8; ++df) {
                    f32x4 t4 = o[mf][df];
                    t4[0] *= alr[0]; t4[1] *= alr[1]; t4[2] *= alr[2]; t4[3] *= alr[3];
                    o[mf][df] = t4;
                }
            }
        }
        // ---- P = exp (in-lane), l-sum, linear b64 P-store (pad-72 rows) ----
#pragma unroll
        for (int mf = 0; mf < 2; ++mf) {
            const int qrow = mf * 16 + ln;
            float ps = 0.f;
#pragma unroll
            for (int nf = 0; nf < 4; ++nf) {
                bf16_t pv[4];
#pragma unroll
                for (int r = 0; r < 4; ++r) {
                    float p = exp2f((sa[mf][nf][r] - mrun[mf]) * L2E);
                    ps += p;
                    pv[r] = (bf16_t)p;
                }
                *(uint2*)&Pw[qrow * 72 + nf * 16 + g * 4] = *(uint2*)pv;
            }
            ps += __shfl_xor(ps, 16);
            ps += __shfl_xor(ps, 32);
            lrun[mf] += ps;
        }
        // ---- PV from LDS V tile: kc halves sequentially ----
#pragma unroll
        for (int kc = 0; kc < 2; ++kc) {
            bf16x8 vf[8];
#pragma unroll
            for (int df = 0; df < 8; ++df)
                vf[df] = *(const bf16x8*)&Vl2[cur][((df * 2 + kc) * 4 + g) * 128 + ln * 8];
#pragma unroll
            for (int mf = 0; mf < 2; ++mf) {
                bf16x8 pa = *(const bf16x8*)&Pw[(mf * 16 + ln) * 72 + kc * 32 + g * 8];
#pragma unroll
                for (int df = 0; df < 8; ++df)
                    o[mf][df] = __builtin_amdgcn_mfma_f32_16x16x32_bf16(pa, vf[df], o[mf][df], 0, 0, 0);
            }
        }
        __syncthreads();   // drains staged loads for t+1; guards buffer reuse
        cur ^= 1;
    }

    // epilogue: o rows are q = qw0 + mf*16 + g*4 + r; 1/l fetched via shfl
#pragma unroll
    for (int mf = 0; mf < 2; ++mf) {
        float linv[4];
#pragma unroll
        for (int r = 0; r < 4; ++r)
            linv[r] = 1.f / __shfl(lrun[mf], (l & 48) | (g * 4 + r));
#pragma unroll
        for (int df = 0; df < 8; ++df)
#pragma unroll
            for (int r = 0; r < 4; ++r) {
                float v = o[mf][df][r] * linv[r];
                size_t orow = (size_t)(b * Sc + qw0 + mf * 16 + g * 4 + r) * (NQc * Dc) + h * Dc + df * 16 + ln;
                attn[orow] = (bf16_t)v;
            }
    }
}

extern "C" void kernel_launch(void* const* d_in, const int* in_sizes, int n_in,
                              void* d_out, int out_size, void* d_ws, size_t ws_size,
                              hipStream_t stream) {
    const float* x      = (const float*)d_in[0];
    const float* cosT   = (const float*)d_in[2];
    const float* sinT   = (const float*)d_in[3];
    const float* kcache = (const float*)d_in[4];
    const float* vcache = (const float*)d_in[5];
    const float* q_w    = (const float*)d_in[6];
    const float* q_b    = (const float*)d_in[7];
    const float* k_w    = (const float*)d_in[8];
    const float* k_b    = (const float*)d_in[9];
    const float* v_w    = (const float*)d_in[10];
    const float* v_b    = (const float*)d_in[11];
    const float* o_w    = (const float*)d_in[12];

    char* ws = (char*)d_ws;
    size_t off = 0;
    auto alloc = [&](size_t bytes) {
        void* p = ws + off;
        off += (bytes + 255) & ~(size_t)255;
        return p;
    };
    bf16_t* xb   = (bf16_t*)alloc((size_t)Mrows * HIDc * 2);        // reused as attn out
    bf16_t* wqkv = (bf16_t*)alloc((size_t)Bc * Tc * NQc * Dc * 4);  // reused as kfr+vfr
    bf16_t* owb  = (bf16_t*)alloc((size_t)HIDc * HIDc * 2);
    bf16_t* qkv  = (bf16_t*)alloc((size_t)Mrows * NQKV * 2);
    float*  bias = (float*)alloc((size_t)NQKV * 4);
    if (off > ws_size) {
        fprintf(stderr, "WS too small: need %zu have %zu\n", off, ws_size);
        return;
    }
    bf16_t* attn  = xb;
    bf16_t* kfr = wqkv;                                   // 33.55 MB per-head frags
    bf16_t* vfr = wqkv + (size_t)Bc * NQc * Tc * Dc;      // 33.55 MB

    float* out_o = (float*)d_out;
    float* out_k = out_o + (size_t)Mrows * HIDc;
    float* out_v = out_k + (size_t)Bc * Tc * NQc * Dc;

    // fused converts: x->xb, q_w/k_w/v_w->wqkv, o_w->owb (one launch)
    const long n0 = (long)Mrows * HIDc / 4;
    const long n1 = (long)NQc * Dc * HIDc / 4;
    const long n2 = (long)NKVc * Dc * HIDc / 4;
    const long n4 = (long)HIDc * HIDc / 4;
    k_cvt5<<<4096, 256, 0, stream>>>(
        x, q_w, k_w, v_w, o_w,
        xb, wqkv, wqkv + (size_t)NQc * Dc * HIDc, wqkv + (size_t)(NQc + NKVc) * Dc * HIDc, owb,
        n0, n0 + n1, n0 + n1 + n2, n0 + n1 + 2 * n2, n0 + n1 + 2 * n2 + n4);
    (void)hipMemcpyAsync(bias, q_b, (size_t)NQc * Dc * 4, hipMemcpyDeviceToDevice, stream);
    (void)hipMemcpyAsync(bias + NQc * Dc, k_b, (size_t)NKVc * Dc * 4, hipMemcpyDeviceToDevice, stream);
    (void)hipMemcpyAsync(bias + (NQc + NKVc) * Dc, v_b, (size_t)NKVc * Dc * 4, hipMemcpyDeviceToDevice, stream);

    k_gemm<128, true, true><<<dim3(NQKV / 128, Mrows / 128), 256, 0, stream>>>(
        xb, wqkv, bias, qkv, Mrows, NQKV, HIDc);
    // weights in wqkv are dead after this GEMM; kfr/vfr alias the region and
    // are written only by stream-ordered later kernels.
    k_rope_q<<<Mrows, 256, 0, stream>>>(qkv, cosT, sinT);
    k_ropekv<<<dim3(16, 8, 2), 256, 0, stream>>>(qkv, cosT, sinT, out_k, out_v, kfr, vfr);
    k_cache<<<dim3(16, 32, 2), 256, 0, stream>>>(kcache, vcache, out_k, out_v, kfr, vfr);
    k_attn<<<256, 512, 0, stream>>>(qkv, kfr, vfr, attn);
    k_gemm<64, false, false><<<dim3(HIDc / 128, Mrows / 64), 256, 0, stream>>>(
        attn, owb, nullptr, d_out, Mrows, HIDc, HIDc);
}